// Round 1
// baseline (291.760 us; speedup 1.0000x reference)
//
#include <hip/hip_runtime.h>
#include <cstdint>

#define NSEQ 2048
#define DIM  768
#define NH   12
#define HD   64

typedef __attribute__((ext_vector_type(8))) short bf16x8;
typedef __attribute__((ext_vector_type(4))) float f32x4;
typedef unsigned short u16;

#define MFMA16(a,b,c) __builtin_amdgcn_mfma_f32_16x16x32_bf16(a,b,c,0,0,0)

// q' = q * HEAD_DIM^-0.5 * log2(e)  -> attention uses exp2 directly
#define QSCALE 0.1803368801111204f

__device__ __forceinline__ u16 f2bf(float f){
  unsigned u = __builtin_bit_cast(unsigned, f);
  return (u16)((u + 0x7fffu + ((u >> 16) & 1u)) >> 16);   // RNE
}

typedef __attribute__((address_space(1))) void gvoid_t;
typedef __attribute__((address_space(3))) void lvoid_t;
__device__ __forceinline__ void g2l16(const void* g, void* l){
  // async global->LDS, 16B/lane; LDS dst = wave-uniform base + lane*16
  __builtin_amdgcn_global_load_lds((gvoid_t*)g, (lvoid_t*)l, 16, 0, 0);
}

// ---------------------------------------------------------------------------
// Kernel 0: fp32 -> bf16 conversion of x and the three weight matrices.
// x: 6291456 floats = 1572864 float4 = 6144 blocks; each w: 576 blocks.
// ---------------------------------------------------------------------------
__global__ __launch_bounds__(256) void convert_all(
    const float* __restrict__ x,  const float* __restrict__ wq,
    const float* __restrict__ wk, const float* __restrict__ wv,
    u16* __restrict__ xb, u16* __restrict__ wb){
  int blk = blockIdx.x, tid = threadIdx.x;
  const float* src; u16* dst; long idx;
  if (blk < 6144){ src = x; dst = xb; idx = (long)blk*256 + tid; }
  else {
    int r = blk - 6144; int s = r / 576; r -= s*576;
    src = (s==0) ? wq : (s==1) ? wk : wv;
    dst = wb + (long)s * (768*768);
    idx = (long)r*256 + tid;
  }
  float4 v = ((const float4*)src)[idx];
  ushort4 o;
  o.x = f2bf(v.x); o.y = f2bf(v.y); o.z = f2bf(v.z); o.w = f2bf(v.w);
  ((ushort4*)dst)[idx] = o;
}

// ---------------------------------------------------------------------------
// Kernel 1: fused QKV projection GEMM.  C[t][o] = sum_j X[t][j]*W[o][j] + b[o]
// M=8192 (t), N=2304 (q|k|v), K=768.  128x128 tile, BK=64, 4 waves of 64x64.
// LDS tiles staged via global_load_lds(16B) with XOR-8 chunk swizzle so the
// ds_read_b128 fragment reads are ~conflict-free.
// Outputs: Q,K as [bh][n][64] bf16 (Q pre-scaled by 0.125*log2e), V as
// V^T [bh][64][n] bf16 (so attention's PV A-operand reads are contiguous).
// ---------------------------------------------------------------------------
__global__ __launch_bounds__(256,2) void qkv_gemm(
    const u16* __restrict__ xb, const u16* __restrict__ wb,
    const float* __restrict__ bq, const float* __restrict__ bk,
    const float* __restrict__ bv,
    u16* __restrict__ Qo, u16* __restrict__ Ko, u16* __restrict__ Vo){
  __shared__ __align__(16) u16 ldsX[128*64];
  __shared__ __align__(16) u16 ldsW[128*64];
  int tid  = threadIdx.x;
  int w    = tid >> 6, lane = tid & 63;
  int bm   = blockIdx.x / 18, bn = blockIdx.x % 18;
  int wm   = w >> 1, wn = w & 1;
  int l15  = lane & 15, g = lane >> 4;
  int srow = lane >> 3;                    // 0..7
  int scol = ((lane & 7) ^ srow) * 8;      // swizzled element col within BK=64

  const u16* xg = xb + (long)bm*128*768;
  const u16* wg = wb + (long)bn*128*768;

  f32x4 acc[4][4] = {};

  for (int k0 = 0; k0 < 768; k0 += 64){
    if (k0) __syncthreads();
    #pragma unroll
    for (int j = 0; j < 4; j++){
      int rr = (w*4 + j)*8 + srow;         // tile row 0..127
      g2l16(xg + (long)rr*768 + k0 + scol, &ldsX[(w*4 + j)*512]);
      g2l16(wg + (long)rr*768 + k0 + scol, &ldsW[(w*4 + j)*512]);
    }
    __syncthreads();                        // drains vmcnt -> LDS visible
    #pragma unroll
    for (int ks = 0; ks < 2; ks++){
      bf16x8 af[4], bfr[4];
      #pragma unroll
      for (int im = 0; im < 4; im++){
        int row = wm*64 + im*16 + l15;
        af[im] = *(const bf16x8*)&ldsX[row*64 + (((ks*4 + g) ^ (row & 7))*8)];
      }
      #pragma unroll
      for (int in = 0; in < 4; in++){
        int row = wn*64 + in*16 + l15;
        bfr[in] = *(const bf16x8*)&ldsW[row*64 + (((ks*4 + g) ^ (row & 7))*8)];
      }
      #pragma unroll
      for (int im = 0; im < 4; im++)
        #pragma unroll
        for (int in = 0; in < 4; in++)
          acc[im][in] = MFMA16(af[im], bfr[in], acc[im][in]);
    }
  }

  // epilogue: C layout col=lane&15 (=o), row=(lane>>4)*4+reg (=t)
  int seg = bn / 6;                         // 0=Q 1=K 2=V (768-aligned blocks)
  const float* bias = (seg==0) ? bq : (seg==1) ? bk : bv;
  #pragma unroll
  for (int in = 0; in < 4; in++){
    int o  = bn*128 + wn*64 + in*16 + l15;
    int oo = o - seg*768;
    int h  = oo >> 6, d = oo & 63;
    float bb = bias[oo];
    #pragma unroll
    for (int im = 0; im < 4; im++){
      int t  = bm*128 + wm*64 + im*16 + g*4;
      int bi = t >> 11, n0 = t & 2047;
      f32x4 a = acc[im][in];
      if (seg == 2){
        ushort4 pk;
        pk.x = f2bf(a[0] + bb); pk.y = f2bf(a[1] + bb);
        pk.z = f2bf(a[2] + bb); pk.w = f2bf(a[3] + bb);
        *(ushort4*)&Vo[((long)(bi*NH + h)*HD + d)*NSEQ + n0] = pk;   // V^T
      } else if (seg == 0){
        #pragma unroll
        for (int r = 0; r < 4; r++)
          Qo[((long)(bi*NH + h)*NSEQ + n0 + r)*HD + d] = f2bf((a[r] + bb)*QSCALE);
      } else {
        #pragma unroll
        for (int r = 0; r < 4; r++)
          Ko[((long)(bi*NH + h)*NSEQ + n0 + r)*HD + d] = f2bf(a[r] + bb);
      }
    }
  }
}

// ---------------------------------------------------------------------------
// Kernel 2: flash attention fwd. One wave owns (bh, 64 q-rows); waves fully
// independent (no barriers). Computes T = K*Q^T (so softmax rows are
// lane-aligned: col=lane&15=r), online softmax in exp2 domain, P goes through
// a per-wave LDS buffer (padded 80B rows) into B-operand layout, then
// O^T += V^T * P^T.  Epilogue: divide by l, coalesced float4 stores.
// ---------------------------------------------------------------------------
__global__ __launch_bounds__(128,2) void attn(
    const u16* __restrict__ Q, const u16* __restrict__ K,
    const u16* __restrict__ VT, float* __restrict__ out){
  __shared__ __align__(16) u16 plds[2][64*40];   // per-wave 64 rows x 40 u16
  int tid = threadIdx.x;
  int w   = tid >> 6, lane = tid & 63;
  int gw  = blockIdx.x*2 + w;
  int bh  = gw >> 5, qb = gw & 31;
  int b   = bh / NH, h = bh - b*NH;
  int l15 = lane & 15, g = lane >> 4;
  u16* pbuf = &plds[w][0];

  const u16* Qb = Q  + (long)bh*NSEQ*HD;
  const u16* Kb = K  + (long)bh*NSEQ*HD;
  const u16* Vb = VT + (long)bh*HD*NSEQ;

  // Q fragments (B-operand, n=r, k=d), kept in registers for the whole pass
  bf16x8 qf[4][2];
  #pragma unroll
  for (int in = 0; in < 4; in++)
    #pragma unroll
    for (int ks = 0; ks < 2; ks++)
      qf[in][ks] = *(const bf16x8*)&Qb[(long)(qb*64 + in*16 + l15)*HD + ks*32 + g*8];

  f32x4 oa[4][4] = {};                      // O^T tiles [d-tile][r-tile]
  float mi[4] = {-1e30f,-1e30f,-1e30f,-1e30f};
  float li[4] = {0.f,0.f,0.f,0.f};

  for (int c0 = 0; c0 < NSEQ; c0 += 32){
    bf16x8 kf[2][2];
    #pragma unroll
    for (int cm = 0; cm < 2; cm++)
      #pragma unroll
      for (int ks = 0; ks < 2; ks++)
        kf[cm][ks] = *(const bf16x8*)&Kb[(long)(c0 + cm*16 + l15)*HD + ks*32 + g*8];
    bf16x8 vf[4];
    #pragma unroll
    for (int dm = 0; dm < 4; dm++)
      vf[dm] = *(const bf16x8*)&Vb[(long)(dm*16 + l15)*NSEQ + c0 + g*8];

    // T[c][r] = sum_d K[c][d] * Q[r][d]   (logits already *0.125*log2e via Q)
    f32x4 T[2][4];
    #pragma unroll
    for (int cm = 0; cm < 2; cm++)
      #pragma unroll
      for (int in = 0; in < 4; in++){
        f32x4 t = {0.f,0.f,0.f,0.f};
        t = MFMA16(kf[cm][0], qf[in][0], t);
        t = MFMA16(kf[cm][1], qf[in][1], t);
        T[cm][in] = t;
      }

    // online softmax per r-tile; lane's col r = in*16 + l15
    #pragma unroll
    for (int in = 0; in < 4; in++){
      float mx = fmaxf(fmaxf(fmaxf(T[0][in][0], T[0][in][1]),
                             fmaxf(T[0][in][2], T[0][in][3])),
                       fmaxf(fmaxf(T[1][in][0], T[1][in][1]),
                             fmaxf(T[1][in][2], T[1][in][3])));
      mx = fmaxf(mx, __shfl_xor(mx, 16));
      mx = fmaxf(mx, __shfl_xor(mx, 32));
      float mnew = fmaxf(mi[in], mx);
      float al   = exp2f(mi[in] - mnew);
      mi[in] = mnew;
      float s = 0.f;
      ushort4 pk[2];
      #pragma unroll
      for (int cm = 0; cm < 2; cm++){
        float p0 = exp2f(T[cm][in][0] - mnew);
        float p1 = exp2f(T[cm][in][1] - mnew);
        float p2 = exp2f(T[cm][in][2] - mnew);
        float p3 = exp2f(T[cm][in][3] - mnew);
        s += (p0 + p1) + (p2 + p3);
        pk[cm].x = f2bf(p0); pk[cm].y = f2bf(p1);
        pk[cm].z = f2bf(p2); pk[cm].w = f2bf(p3);
      }
      s += __shfl_xor(s, 16);
      s += __shfl_xor(s, 32);
      li[in] = li[in]*al + s;
      #pragma unroll
      for (int dm = 0; dm < 4; dm++) oa[dm][in] *= al;
      // P^T stored [r][c_local]: lane's c_local = cm*16 + g*4 + reg
      #pragma unroll
      for (int cm = 0; cm < 2; cm++)
        *(ushort4*)&pbuf[(in*16 + l15)*40 + cm*16 + g*4] = pk[cm];
    }

    // same-wave LDS round-trip (compiler inserts lgkmcnt wait; no barrier)
    bf16x8 pf[4];
    #pragma unroll
    for (int in = 0; in < 4; in++)
      pf[in] = *(const bf16x8*)&pbuf[(in*16 + l15)*40 + g*8];
    #pragma unroll
    for (int dm = 0; dm < 4; dm++)
      #pragma unroll
      for (int in = 0; in < 4; in++)
        oa[dm][in] = MFMA16(vf[dm], pf[in], oa[dm][in]);
  }

  // epilogue: O^T col=lane&15=r, rows=d -> contiguous d per lane -> float4
  #pragma unroll
  for (int in = 0; in < 4; in++){
    float inv = 1.f / li[in];
    int r = qb*64 + in*16 + l15;
    #pragma unroll
    for (int dm = 0; dm < 4; dm++){
      f32x4 v = oa[dm][in];
      v *= inv;
      int d = dm*16 + g*4;
      *(f32x4*)&out[(long)(b*NSEQ + r)*DIM + h*HD + d] = v;
    }
  }
}

// ---------------------------------------------------------------------------
extern "C" void kernel_launch(void* const* d_in, const int* in_sizes, int n_in,
                              void* d_out, int out_size, void* d_ws, size_t ws_size,
                              hipStream_t stream){
  (void)in_sizes; (void)n_in; (void)out_size; (void)ws_size;
  const float* x  = (const float*)d_in[0];
  const float* wq = (const float*)d_in[1];
  const float* bq = (const float*)d_in[2];
  const float* wk = (const float*)d_in[3];
  const float* bk = (const float*)d_in[4];
  const float* wv = (const float*)d_in[5];
  const float* bv = (const float*)d_in[6];

  char* ws = (char*)d_ws;
  u16* xb = (u16*)ws;                       // [8192][768]        12,582,912 B
  u16* wb = (u16*)(ws + 12582912);          // [2304][768]         3,538,944 B
  u16* Qp = (u16*)(ws + 16121856);          // [48][2048][64]     12,582,912 B
  u16* Kp = (u16*)(ws + 28704768);          // [48][2048][64]     12,582,912 B
  u16* Vp = (u16*)(ws + 41287680);          // [48][64][2048]     12,582,912 B
                                            // total ~53.9 MB of workspace

  convert_all<<<7872, 256, 0, stream>>>(x, wq, wk, wv, xb, wb);
  qkv_gemm<<<1152, 256, 0, stream>>>(xb, wb, bq, bk, bv, Qp, Kp, Vp);
  attn<<<768, 128, 0, stream>>>(Qp, Kp, Vp, (float*)d_out);
}